// Round 1
// baseline (384.462 us; speedup 1.0000x reference)
//
#include <hip/hip_runtime.h>
#include <hip/hip_bf16.h>
#include <stdint.h>

#define L_DIM 384
#define MD    256      // M_DIM
#define CC    32       // C
#define ZD    128      // Z_DIM
#define NB    512      // N (batch) = K of the big GEMM
#define K2    1024     // C*C
#define MROWS 12288    // L*C

typedef __attribute__((ext_vector_type(4))) float  f32x4;
typedef __attribute__((ext_vector_type(8))) short  bf16x8;

typedef __attribute__((address_space(1))) unsigned char* gcp;
typedef __attribute__((address_space(3))) unsigned char* lcp;

__device__ __forceinline__ unsigned short f2bf(float x) {
    union { float f; unsigned u; } v; v.f = x;
    unsigned r = v.u + 0x7fffu + ((v.u >> 16) & 1u);   // round-to-nearest-even
    return (unsigned short)(r >> 16);
}

__device__ __forceinline__ uint2 pack4(unsigned short a, unsigned short b,
                                       unsigned short c, unsigned short d) {
    uint2 r; r.x = (unsigned)a | ((unsigned)b << 16);
    r.y = (unsigned)c | ((unsigned)d << 16); return r;
}

// ---------------------------------------------------------------------------
// w3 (1024x128 f32) -> w3t (128x1024 bf16), transposed so the epilogue GEMM's
// B-operand (k2-contiguous per lane) stages linearly.
__global__ __launch_bounds__(256) void prep_w3_kernel(const float* __restrict__ w3,
                                                      unsigned short* __restrict__ w3t) {
    int idx = blockIdx.x * 256 + threadIdx.x;      // 131072 total
    int k2 = idx >> 7, zc = idx & 127;
    w3t[(size_t)zc * K2 + k2] = f2bf(w3[idx]);
}

// ---------------------------------------------------------------------------
// Kernel A: LayerNorm + dual projection (a = o@w2+b2, b = o@w1+b1) via MFMA.
// Block = 2 l-values x 32 n-values (64 rows), 4 waves, wave = 16 rows.
// Writes At[ia][n], Bt[jb][n] bf16 (K-contiguous for the big GEMM).
__global__ __launch_bounds__(256) void ln_proj_kernel(
    const float* __restrict__ mm, const float* __restrict__ gamma, const float* __restrict__ beta,
    const float* __restrict__ w1, const float* __restrict__ b1,
    const float* __restrict__ w2, const float* __restrict__ b2,
    unsigned short* __restrict__ At, unsigned short* __restrict__ Bt)
{
    __shared__ unsigned short sm[32768];           // 64 KB: o[0,32KB) w[32KB,64KB)
    char* const o_b = (char*)&sm[0];
    char* const w_b = (char*)&sm[16384];

    const int tid = threadIdx.x, wv = tid >> 6, lane = tid & 63;
    const int l0 = blockIdx.y * 2;
    const int n0 = blockIdx.x * 32;

    // stage weights: w_lds[c][d] bf16, row pitch 512B, XOR-swizzled (bank fix)
    for (int idx = tid; idx < 64 * MD; idx += 256) {
        int c = idx & 63, d = idx >> 6;
        float v = (c < CC) ? w2[d * CC + c] : w1[d * CC + (c - CC)];
        *(unsigned short*)(w_b + c * 512 + ((d * 2) ^ ((c & 7) << 4))) = f2bf(v);
    }

    const int l_loc = wv >> 1;
    const int nbase = (wv & 1) << 4;
    const int l_g = l0 + l_loc;
    f32x4 g4 = *(const f32x4*)(gamma + lane * 4);
    f32x4 e4 = *(const f32x4*)(beta + lane * 4);

    #pragma unroll 4
    for (int r = 0; r < 16; ++r) {
        int row_loc = l_loc * 32 + nbase + r;
        int n_g = n0 + nbase + r;
        const float* src = mm + ((size_t)n_g * L_DIM + l_g) * MD + lane * 4;
        f32x4 x = *(const f32x4*)src;
        float s  = x[0] + x[1] + x[2] + x[3];
        float s2 = x[0]*x[0] + x[1]*x[1] + x[2]*x[2] + x[3]*x[3];
        #pragma unroll
        for (int off = 32; off > 0; off >>= 1) {
            s  += __shfl_xor(s,  off);
            s2 += __shfl_xor(s2, off);
        }
        float mu  = s * (1.0f / MD);
        float var = s2 * (1.0f / MD) - mu * mu;
        float rs  = rsqrtf(var + 1e-5f);
        unsigned short o0 = f2bf((x[0] - mu) * rs * g4[0] + e4[0]);
        unsigned short o1 = f2bf((x[1] - mu) * rs * g4[1] + e4[1]);
        unsigned short o2 = f2bf((x[2] - mu) * rs * g4[2] + e4[2]);
        unsigned short o3 = f2bf((x[3] - mu) * rs * g4[3] + e4[3]);
        *(uint2*)(o_b + row_loc * 512 + ((lane * 8) ^ ((row_loc & 7) << 4))) = pack4(o0, o1, o2, o3);
    }
    __syncthreads();

    // MFMA 64x64x256: wave handles its own 16 rows x 64 output cols
    f32x4 acc[4] = {{0,0,0,0},{0,0,0,0},{0,0,0,0},{0,0,0,0}};
    const int lrow = lane & 15;
    const int kq = (lane >> 4) << 4;               // k byte offset within 64B group
    const int arow = wv * 16 + lrow;
    #pragma unroll
    for (int ks = 0; ks < 8; ++ks) {
        bf16x8 a = *(const bf16x8*)(o_b + arow * 512 + ((ks * 64 + kq) ^ ((arow & 7) << 4)));
        #pragma unroll
        for (int nf = 0; nf < 4; ++nf) {
            int c = nf * 16 + lrow;
            bf16x8 b = *(const bf16x8*)(w_b + c * 512 + ((ks * 64 + kq) ^ ((c & 7) << 4)));
            acc[nf] = __builtin_amdgcn_mfma_f32_16x16x32_bf16(a, b, acc[nf], 0, 0, 0);
        }
    }

    // epilogue: C-frag col=lane&15, row=(lane>>4)*4+r -> 4 consecutive n, pack 8B store
    const int rr0 = wv * 16 + ((lane >> 4) << 2);
    const int n_gw = n0 + (rr0 & 31);
    const int l_gw = l0 + (rr0 >> 5);
    #pragma unroll
    for (int nf = 0; nf < 4; ++nf) {
        int c = nf * 16 + lrow;
        float bias = (c < CC) ? b2[c] : b1[c - CC];
        unsigned short ob0 = f2bf(acc[nf][0] + bias);
        unsigned short ob1 = f2bf(acc[nf][1] + bias);
        unsigned short ob2 = f2bf(acc[nf][2] + bias);
        unsigned short ob3 = f2bf(acc[nf][3] + bias);
        unsigned short* dst = ((c < CC) ? At : Bt) + (size_t)(l_gw * CC + (c & 31)) * NB + n_gw;
        *(uint2*)dst = pack4(ob0, ob1, ob2, ob3);
    }
}

// ---------------------------------------------------------------------------
// Kernel B: op-tile GEMM (128x128 tile, K=512, 2-phase dbuf) + fused w3 epilogue.
__global__ __launch_bounds__(256) void opm_kernel(
    const unsigned short* __restrict__ At, const unsigned short* __restrict__ Bt,
    const unsigned short* __restrict__ w3t, const float* __restrict__ b3,
    float* __restrict__ Z)
{
    __shared__ unsigned short sm[32768];           // 64 KB union
    char* const base = (char*)&sm[0];

    const int tid = threadIdx.x, wv = tid >> 6, lane = tid & 63;
    const int i0 = blockIdx.x * 128, j0 = blockIdx.y * 128;
    const int lrow = lane & 15;
    const int kq = (lane >> 4) << 4;
    const int srow = lane >> 3;                              // staging: row within 8
    const int skoff = ((lane & 7) ^ (srow & 7)) << 3;        // pre-swizzled k elem offset

    // main staging: A tiles [0,32KB) dbuf, B tiles [32KB,64KB) dbuf; rows of 128B
    auto stage_main = [&](int s, int t) {
        const int k0 = t * 64;
        #pragma unroll
        for (int g = 0; g < 4; ++g) {
            int rowA = g * 32 + wv * 8;
            const unsigned short* sa = At + (size_t)(i0 + rowA + srow) * NB + k0 + skoff;
            __builtin_amdgcn_global_load_lds((gcp)sa, (lcp)(base + s * 16384 + rowA * 128), 16, 0, 0);
            const unsigned short* sb = Bt + (size_t)(j0 + rowA + srow) * NB + k0 + skoff;
            __builtin_amdgcn_global_load_lds((gcp)sb, (lcp)(base + 32768 + s * 16384 + rowA * 128), 16, 0, 0);
        }
    };

    f32x4 acc[4][4] = {};
    const int wr = (wv >> 1) * 64, wc = (wv & 1) * 64;

    stage_main(0, 0);
    __syncthreads();
    int cur = 0;
    for (int t = 0; t < 8; ++t) {
        if (t < 7) stage_main(cur ^ 1, t + 1);
        const char* ab = base + cur * 16384;
        const char* bb = base + 32768 + cur * 16384;
        #pragma unroll
        for (int ks = 0; ks < 2; ++ks) {
            bf16x8 av[4], bv[4];
            #pragma unroll
            for (int mf = 0; mf < 4; ++mf) {
                int row = wr + mf * 16 + lrow;
                av[mf] = *(const bf16x8*)(ab + row * 128 + ((ks * 64 + kq) ^ ((row & 7) << 4)));
            }
            #pragma unroll
            for (int nf = 0; nf < 4; ++nf) {
                int row = wc + nf * 16 + lrow;
                bv[nf] = *(const bf16x8*)(bb + row * 128 + ((ks * 64 + kq) ^ ((row & 7) << 4)));
            }
            #pragma unroll
            for (int mf = 0; mf < 4; ++mf)
                #pragma unroll
                for (int nf = 0; nf < 4; ++nf)
                    acc[mf][nf] = __builtin_amdgcn_mfma_f32_16x16x32_bf16(av[mf], bv[nf], acc[mf][nf], 0, 0, 0);
        }
        __syncthreads();
        cur ^= 1;
    }

    // ---- fused w3 epilogue ----
    // per-wave w3 slice staging: region [32KB,64KB): wave wv -> [32][64] dbuf
    auto stage_w3 = [&](int s, int ck) {
        #pragma unroll
        for (int g = 0; g < 4; ++g) {
            int zr = wv * 32 + g * 8;
            const unsigned short* sw = w3t + (size_t)(zr + srow) * K2 + ck * 64 + skoff;
            __builtin_amdgcn_global_load_lds((gcp)sw,
                (lcp)(base + 32768 + wv * 8192 + s * 4096 + g * 1024), 16, 0, 0);
        }
    };
    stage_w3(0, 0);   // overlap with op writes

    // write op tile (scaled, bf16) to LDS [16 ij][1024 ab], pitch 2048B, swizzled
    char* const opb = base;
    const float scale = 1.0f / (float)NB;
    #pragma unroll
    for (int mf = 0; mf < 4; ++mf) {
        #pragma unroll
        for (int nf = 0; nf < 4; ++nf) {
            int colb = wc + nf * 16 + lrow;
            #pragma unroll
            for (int r = 0; r < 4; ++r) {
                int row = wr + mf * 16 + ((lane >> 4) << 2) + r;
                int p = ((row >> 5) << 2) | (colb >> 5);
                int abx = (((row & 31) << 5) | (colb & 31)) << 1;
                *(unsigned short*)(opb + p * 2048 + (abx ^ ((p & 7) << 4))) =
                    f2bf(acc[mf][nf][r] * scale);
            }
        }
    }
    __syncthreads();   // op visible to all; also drains w3 chunk-0 stage

    // z[16 pairs][128] = op[16][1024] @ w3t^T, K2 in 16 chunks of 64, per-wave 32 z-cols
    f32x4 acc2[2] = {};
    int cur2 = 0;
    for (int ck = 0; ck < 16; ++ck) {
        if (ck < 15) stage_w3(cur2 ^ 1, ck + 1);
        const char* wb = base + 32768 + wv * 8192 + cur2 * 4096;
        #pragma unroll
        for (int ks = 0; ks < 2; ++ks) {
            bf16x8 a = *(const bf16x8*)(opb + lrow * 2048 +
                         ((ck * 128 + ks * 64 + kq) ^ ((lrow & 7) << 4)));
            #pragma unroll
            for (int nf = 0; nf < 2; ++nf) {
                int rloc = nf * 16 + lrow;
                bf16x8 b = *(const bf16x8*)(wb + rloc * 128 + ((ks * 64 + kq) ^ ((rloc & 7) << 4)));
                acc2[nf] = __builtin_amdgcn_mfma_f32_16x16x32_bf16(a, b, acc2[nf], 0, 0, 0);
            }
        }
        asm volatile("s_waitcnt vmcnt(0)" ::: "memory");
        cur2 ^= 1;
    }

    // write z
    const int pq = (lane >> 4) << 2;
    #pragma unroll
    for (int nf = 0; nf < 2; ++nf) {
        int zc = wv * 32 + nf * 16 + lrow;
        float bias = b3[zc];
        #pragma unroll
        for (int r = 0; r < 4; ++r) {
            int p = pq + r;
            int ii = (i0 >> 5) + (p >> 2);
            int jj = (j0 >> 5) + (p & 3);
            Z[((size_t)ii * L_DIM + jj) * ZD + zc] = acc2[nf][r] + bias;
        }
    }
}

// ---------------------------------------------------------------------------
extern "C" void kernel_launch(void* const* d_in, const int* in_sizes, int n_in,
                              void* d_out, int out_size, void* d_ws, size_t ws_size,
                              hipStream_t stream)
{
    const float* mm    = (const float*)d_in[0];
    const float* gamma = (const float*)d_in[1];
    const float* beta  = (const float*)d_in[2];
    const float* w1    = (const float*)d_in[3];
    const float* b1    = (const float*)d_in[4];
    const float* w2    = (const float*)d_in[5];
    const float* b2    = (const float*)d_in[6];
    const float* w3    = (const float*)d_in[7];
    const float* b3    = (const float*)d_in[8];

    unsigned short* At  = (unsigned short*)d_ws;                 // 12288x512 bf16
    unsigned short* Bt  = At + (size_t)MROWS * NB;               // 12288x512 bf16
    unsigned short* w3t = Bt + (size_t)MROWS * NB;               // 128x1024 bf16

    prep_w3_kernel<<<512, 256, 0, stream>>>(w3, w3t);
    ln_proj_kernel<<<dim3(16, 192), 256, 0, stream>>>(mm, gamma, beta, w1, b1, w2, b2, At, Bt);
    opm_kernel<<<dim3(96, 96), 256, 0, stream>>>(At, Bt, w3t, b3, (float*)d_out);
}

// Round 2
// 279.457 us; speedup vs baseline: 1.3757x; 1.3757x over previous
//
#include <hip/hip_runtime.h>
#include <hip/hip_bf16.h>
#include <stdint.h>

#define L_DIM 384
#define MD    256      // M_DIM
#define CC    32       // C
#define ZD    128      // Z_DIM
#define NB    512      // N (batch) = K of the big GEMM
#define K2    1024     // C*C
#define MROWS 12288    // L*C

typedef __attribute__((ext_vector_type(4))) float  f32x4;
typedef __attribute__((ext_vector_type(8))) short  bf16x8;

typedef __attribute__((address_space(1))) unsigned char* gcp;
typedef __attribute__((address_space(3))) unsigned char* lcp;

#define SBAR()  __builtin_amdgcn_s_barrier()
#define LGKM0() asm volatile("s_waitcnt lgkmcnt(0)" ::: "memory")
#define VMW(n)  asm volatile("s_waitcnt vmcnt(" #n ")" ::: "memory")
#define PRIO1() __builtin_amdgcn_s_setprio(1)
#define PRIO0() __builtin_amdgcn_s_setprio(0)

__device__ __forceinline__ unsigned short f2bf(float x) {
    union { float f; unsigned u; } v; v.f = x;
    unsigned r = v.u + 0x7fffu + ((v.u >> 16) & 1u);   // round-to-nearest-even
    return (unsigned short)(r >> 16);
}

__device__ __forceinline__ uint2 pack4(unsigned short a, unsigned short b,
                                       unsigned short c, unsigned short d) {
    uint2 r; r.x = (unsigned)a | ((unsigned)b << 16);
    r.y = (unsigned)c | ((unsigned)d << 16); return r;
}

// ---------------------------------------------------------------------------
// prep: pack w3 (1024x128 f32) into MFMA B-fragment order w3frag[ks][zg][lane][8]
// (ks 0..31 over K2, zg 0..7 over Z), and w1/w2 into wfrag[ks][nf][lane][8]
// (ks 0..7 over MD, nf 0..3 over the 64 concatenated channels: c<32 -> w2).
__global__ __launch_bounds__(256) void prep_kernel(
    const float* __restrict__ w1, const float* __restrict__ w2,
    const float* __restrict__ w3,
    unsigned short* __restrict__ w3frag, unsigned short* __restrict__ wfrag)
{
    int idx = blockIdx.x * 256 + threadIdx.x;          // 147456 total
    if (idx < 131072) {
        int e = idx & 7, lane = (idx >> 3) & 63, zg = (idx >> 9) & 7, ks = idx >> 12;
        int k2 = ks * 32 + ((lane >> 4) << 3) + e;
        int z  = zg * 16 + (lane & 15);
        w3frag[idx] = f2bf(w3[(size_t)k2 * ZD + z]);
    } else {
        int j = idx - 131072;                           // 16384
        int e = j & 7, lane = (j >> 3) & 63, nf = (j >> 9) & 3, ks = j >> 11;
        int c = nf * 16 + (lane & 15);
        int d = ks * 32 + ((lane >> 4) << 3) + e;
        float v = (c < CC) ? w2[d * CC + c] : w1[d * CC + (c - CC)];
        wfrag[j] = f2bf(v);
    }
}

// ---------------------------------------------------------------------------
// Kernel A: LayerNorm + dual projection (a = o@w2+b2, b = o@w1+b1) via MFMA.
// Block = 2 l x 32 n (64 rows), 4 waves, 16 rows/wave (wave-private -> no barrier).
// Weights streamed from wfrag (L2). Writes At[ia][n], Bt[jb][n] bf16 (K-contig).
__global__ __launch_bounds__(256, 4) void ln_proj_kernel(
    const float* __restrict__ mm, const float* __restrict__ gamma, const float* __restrict__ beta,
    const unsigned short* __restrict__ wfrag,
    const float* __restrict__ b1, const float* __restrict__ b2,
    unsigned short* __restrict__ At, unsigned short* __restrict__ Bt)
{
    __shared__ alignas(16) char o_b[32768];            // [64 rows][512 B] swizzled

    const int tid = threadIdx.x, wv = tid >> 6, lane = tid & 63;
    const int l0 = blockIdx.y * 2;
    const int n0 = blockIdx.x * 32;

    const int l_loc = wv >> 1;
    const int nbase = (wv & 1) << 4;
    const int l_g = l0 + l_loc;
    f32x4 g4 = *(const f32x4*)(gamma + lane * 4);
    f32x4 e4 = *(const f32x4*)(beta + lane * 4);

    #pragma unroll 4
    for (int r = 0; r < 16; ++r) {
        int row_loc = wv * 16 + r;
        int n_g = n0 + nbase + r;
        const float* src = mm + ((size_t)n_g * L_DIM + l_g) * MD + lane * 4;
        f32x4 x = *(const f32x4*)src;
        float s  = x[0] + x[1] + x[2] + x[3];
        float s2 = x[0]*x[0] + x[1]*x[1] + x[2]*x[2] + x[3]*x[3];
        #pragma unroll
        for (int off = 32; off > 0; off >>= 1) {
            s  += __shfl_xor(s,  off);
            s2 += __shfl_xor(s2, off);
        }
        float mu  = s * (1.0f / MD);
        float var = s2 * (1.0f / MD) - mu * mu;
        float rs  = rsqrtf(var + 1e-5f);
        unsigned short o0 = f2bf((x[0] - mu) * rs * g4[0] + e4[0]);
        unsigned short o1 = f2bf((x[1] - mu) * rs * g4[1] + e4[1]);
        unsigned short o2 = f2bf((x[2] - mu) * rs * g4[2] + e4[2]);
        unsigned short o3 = f2bf((x[3] - mu) * rs * g4[3] + e4[3]);
        *(uint2*)(o_b + row_loc * 512 + ((lane * 8) ^ ((row_loc & 7) << 4))) = pack4(o0, o1, o2, o3);
    }
    // no __syncthreads: each wave reads only its own 16 rows (lgkmcnt-tracked)

    f32x4 acc[4] = {{0,0,0,0},{0,0,0,0},{0,0,0,0},{0,0,0,0}};
    const int lrow = lane & 15;
    const int kq16 = (lane >> 4) << 4;
    const int arow = wv * 16 + lrow;
    #pragma unroll
    for (int ks = 0; ks < 8; ++ks) {
        bf16x8 a = *(const bf16x8*)(o_b + arow * 512 + ((ks * 64 + kq16) ^ ((arow & 7) << 4)));
        #pragma unroll
        for (int nf = 0; nf < 4; ++nf) {
            bf16x8 b = *(const bf16x8*)(wfrag + (size_t)((ks * 4 + nf) * 64 + lane) * 8);
            acc[nf] = __builtin_amdgcn_mfma_f32_16x16x32_bf16(a, b, acc[nf], 0, 0, 0);
        }
    }

    const int rr0 = wv * 16 + ((lane >> 4) << 2);
    const int n_gw = n0 + (rr0 & 31);
    const int l_gw = l0 + (rr0 >> 5);
    #pragma unroll
    for (int nf = 0; nf < 4; ++nf) {
        int c = nf * 16 + lrow;
        float bias = (c < CC) ? b2[c] : b1[c - CC];
        unsigned short ob0 = f2bf(acc[nf][0] + bias);
        unsigned short ob1 = f2bf(acc[nf][1] + bias);
        unsigned short ob2 = f2bf(acc[nf][2] + bias);
        unsigned short ob3 = f2bf(acc[nf][3] + bias);
        unsigned short* dst = ((c < CC) ? At : Bt) + (size_t)(l_gw * CC + (c & 31)) * NB + n_gw;
        *(uint2*)dst = pack4(ob0, ob1, ob2, ob3);
    }
}

// ---------------------------------------------------------------------------
// Kernel B: 256x256 op-tile GEMM, K=512, 8-phase schedule (T3+T4+T5),
// counted vmcnt, + fused single-pass w3 epilogue (op tile = full 128 KB LDS).
__global__ __launch_bounds__(512, 2) void opm_kernel(
    const unsigned short* __restrict__ At, const unsigned short* __restrict__ Bt,
    const unsigned short* __restrict__ w3frag, const float* __restrict__ b3,
    float* __restrict__ Z)
{
    __shared__ alignas(128) char smem[131072];         // A:[2][256][64] B:[2][256][64]
    char* const Ab = smem;
    char* const Bb = smem + 65536;

    const int tid = threadIdx.x, wv = tid >> 6, lane = tid & 63;
    const int i0 = blockIdx.x * 256, j0 = blockIdx.y * 256;
    const int lrow = lane & 15;
    const int kq16 = (lane >> 4) << 4;
    const int wr = (wv >> 2) * 128, wc = (wv & 3) * 64;

    // --- staging: one half-tile = 2 global_load_lds per thread ---
    // A halves: half h -> rows {h*64..h*64+63} u {128+h*64..128+h*64+63}
    // B halves: half h -> cols {64c + h*32 .. +31}, c=0..3
    auto stage = [&](const unsigned short* __restrict__ src, int tile0, int kt,
                     int half, int isA) {
        #pragma unroll
        for (int q = 0; q < 2; ++q) {
            int rl0 = q * 64 + wv * 8;
            int rl  = rl0 + (lane >> 3);
            int rc  = isA ? ((rl  & 63) + ((rl  >> 6) << 7) + half * 64)
                          : ((rl  & 31) + ((rl  >> 5) << 6) + half * 32);
            int rc0 = isA ? ((rl0 & 63) + ((rl0 >> 6) << 7) + half * 64)
                          : ((rl0 & 31) + ((rl0 >> 5) << 6) + half * 32);
            const unsigned short* g = src + (size_t)(tile0 + rc) * NB + kt * 64
                                      + (((lane & 7) ^ (lane >> 3)) << 3);
            char* l = (isA ? Ab : Bb) + (kt & 1) * 32768 + rc0 * 128;  // wave-uniform
            __builtin_amdgcn_global_load_lds((gcp)g, (lcp)l, 16, 0, 0);
        }
    };

    f32x4 acc[8][4] = {};
    bf16x8 av[8], bl[4], bh[4];

    auto rdA = [&](const char* ab, int qrow) {
        #pragma unroll
        for (int mfl = 0; mfl < 4; ++mfl) {
            int row = wr + qrow * 64 + mfl * 16 + lrow;
            const char* p = ab + row * 128;
            av[mfl*2+0] = *(const bf16x8*)(p + ((     kq16) ^ ((row & 7) << 4)));
            av[mfl*2+1] = *(const bf16x8*)(p + ((64 + kq16) ^ ((row & 7) << 4)));
        }
    };
    auto rdB = [&](const char* bb, int qcol, bf16x8* bv) {
        #pragma unroll
        for (int nfl = 0; nfl < 2; ++nfl) {
            int col = wc + qcol * 32 + nfl * 16 + lrow;
            const char* p = bb + col * 128;
            bv[nfl*2+0] = *(const bf16x8*)(p + ((     kq16) ^ ((col & 7) << 4)));
            bv[nfl*2+1] = *(const bf16x8*)(p + ((64 + kq16) ^ ((col & 7) << 4)));
        }
    };
    auto MM = [&](bf16x8* bv, int mbase, int nbase) {
        #pragma unroll
        for (int mfl = 0; mfl < 4; ++mfl)
            #pragma unroll
            for (int nfl = 0; nfl < 2; ++nfl)
                #pragma unroll
                for (int ks = 0; ks < 2; ++ks)
                    acc[mbase+mfl][nbase+nfl] = __builtin_amdgcn_mfma_f32_16x16x32_bf16(
                        av[mfl*2+ks], bv[nfl*2+ks], acc[mbase+mfl][nbase+nfl], 0, 0, 0);
    };

    // --- prologue: stage kt0 + kt1, retire kt0, keep kt1 in flight ---
    stage(At, i0, 0, 0, 1); stage(At, i0, 0, 1, 1);
    stage(Bt, j0, 0, 0, 0); stage(Bt, j0, 0, 1, 0);
    stage(At, i0, 1, 0, 1); stage(At, i0, 1, 1, 1);
    stage(Bt, j0, 1, 0, 0); stage(Bt, j0, 1, 1, 0);
    VMW(8);
    SBAR();

    // --- main loop: 4 iters x 2 K-tiles x 4 phases ---
    for (int t = 0; t < 4; ++t) {
        const int ktc = (2*t + 2) & 7, ktd = (2*t + 3) & 7;
        const char* a0 = Ab;           const char* b0 = Bb;
        const char* a1 = Ab + 32768;   const char* b1 = Bb + 32768;
        // P0
        rdA(a0, 0); rdB(b0, 0, bl);
        SBAR(); LGKM0(); PRIO1(); MM(bl, 0, 0); PRIO0(); SBAR();
        // P1
        rdB(b0, 1, bh); stage(At, i0, ktc, 0, 1);
        SBAR(); LGKM0(); PRIO1(); MM(bh, 0, 2); PRIO0(); SBAR();
        // P2
        rdA(a0, 1); stage(Bt, j0, ktc, 0, 0);
        SBAR(); LGKM0(); PRIO1(); MM(bh, 4, 2); PRIO0(); SBAR();
        // P3
        stage(Bt, j0, ktc, 1, 0);
        SBAR(); LGKM0(); PRIO1(); MM(bl, 4, 0); PRIO0(); VMW(6); SBAR();
        // P4
        rdA(a1, 0); rdB(b1, 0, bl); stage(At, i0, ktc, 1, 1);
        SBAR(); LGKM0(); PRIO1(); MM(bl, 0, 0); PRIO0(); SBAR();
        // P5
        rdB(b1, 1, bh); stage(At, i0, ktd, 0, 1);
        SBAR(); LGKM0(); PRIO1(); MM(bh, 0, 2); PRIO0(); SBAR();
        // P6
        rdA(a1, 1); stage(Bt, j0, ktd, 0, 0);
        SBAR(); LGKM0(); PRIO1(); MM(bh, 4, 2); PRIO0(); SBAR();
        // P7
        stage(Bt, j0, ktd, 1, 0); stage(At, i0, ktd, 1, 1);
        SBAR(); LGKM0(); PRIO1(); MM(bl, 4, 0); PRIO0(); VMW(8); SBAR();
    }

    // --- epilogue: op (scaled, bf16) -> full-LDS [64 pairs][1024 ab], then z ---
    VMW(0);
    __syncthreads();

    char* const opb = smem;
    const float scale = 1.0f / (float)NB;
    #pragma unroll
    for (int mf = 0; mf < 8; ++mf) {
        #pragma unroll
        for (int nf = 0; nf < 4; ++nf) {
            int col = wc + nf * 16 + lrow;
            #pragma unroll
            for (int rr = 0; rr < 4; ++rr) {
                int row = wr + mf * 16 + ((lane >> 4) << 2) + rr;
                int pl = ((row >> 5) << 3) | (col >> 5);
                int k2 = ((row & 31) << 5) | (col & 31);
                *(unsigned short*)(opb + pl * 2048 + ((k2 * 2) ^ ((pl & 7) << 4))) =
                    f2bf(acc[mf][nf][rr] * scale);
            }
        }
    }
    __syncthreads();

    // z[64 pairs][128] = op @ w3 : wave = (2 pair-frags, 2 z-groups), K2 = 32 ks
    f32x4 acc2[2][2] = {};
    const int pfb = (wv >> 2) * 2, zgb = (wv & 3) * 2;
    const int row0 = pfb * 16 + lrow, row1 = row0 + 16;
    #pragma unroll 4
    for (int ks = 0; ks < 32; ++ks) {
        int g = ks * 4 + (lane >> 4);
        bf16x8 p0 = *(const bf16x8*)(opb + row0 * 2048 + ((g * 16) ^ ((row0 & 7) << 4)));
        bf16x8 p1 = *(const bf16x8*)(opb + row1 * 2048 + ((g * 16) ^ ((row1 & 7) << 4)));
        bf16x8 w0 = *(const bf16x8*)(w3frag + (size_t)((ks * 8 + zgb    ) * 64 + lane) * 8);
        bf16x8 w1 = *(const bf16x8*)(w3frag + (size_t)((ks * 8 + zgb + 1) * 64 + lane) * 8);
        acc2[0][0] = __builtin_amdgcn_mfma_f32_16x16x32_bf16(p0, w0, acc2[0][0], 0, 0, 0);
        acc2[0][1] = __builtin_amdgcn_mfma_f32_16x16x32_bf16(p0, w1, acc2[0][1], 0, 0, 0);
        acc2[1][0] = __builtin_amdgcn_mfma_f32_16x16x32_bf16(p1, w0, acc2[1][0], 0, 0, 0);
        acc2[1][1] = __builtin_amdgcn_mfma_f32_16x16x32_bf16(p1, w1, acc2[1][1], 0, 0, 0);
    }

    #pragma unroll
    for (int p = 0; p < 2; ++p) {
        #pragma unroll
        for (int zi = 0; zi < 2; ++zi) {
            int zc = (zgb + zi) * 16 + lrow;
            float bias = b3[zc];
            #pragma unroll
            for (int rr = 0; rr < 4; ++rr) {
                int pl = (pfb + p) * 16 + ((lane >> 4) << 2) + rr;
                int ii = blockIdx.x * 8 + (pl >> 3);
                int jj = blockIdx.y * 8 + (pl & 7);
                Z[((size_t)ii * L_DIM + jj) * ZD + zc] = acc2[p][zi][rr] + bias;
            }
        }
    }
}

// ---------------------------------------------------------------------------
extern "C" void kernel_launch(void* const* d_in, const int* in_sizes, int n_in,
                              void* d_out, int out_size, void* d_ws, size_t ws_size,
                              hipStream_t stream)
{
    const float* mm    = (const float*)d_in[0];
    const float* gamma = (const float*)d_in[1];
    const float* beta  = (const float*)d_in[2];
    const float* w1    = (const float*)d_in[3];
    const float* b1    = (const float*)d_in[4];
    const float* w2    = (const float*)d_in[5];
    const float* b2    = (const float*)d_in[6];
    const float* w3    = (const float*)d_in[7];
    const float* b3    = (const float*)d_in[8];

    unsigned short* At     = (unsigned short*)d_ws;                  // 12288x512
    unsigned short* Bt     = At + (size_t)MROWS * NB;                // 12288x512
    unsigned short* w3frag = Bt + (size_t)MROWS * NB;                // 131072
    unsigned short* wfrag  = w3frag + 131072;                        // 16384

    prep_kernel<<<576, 256, 0, stream>>>(w1, w2, w3, w3frag, wfrag);
    ln_proj_kernel<<<dim3(16, 192), 256, 0, stream>>>(mm, gamma, beta, wfrag, b1, b2, At, Bt);
    opm_kernel<<<dim3(48, 48), 512, 0, stream>>>(At, Bt, w3frag, b3, (float*)d_out);
}

// Round 3
// 258.228 us; speedup vs baseline: 1.4888x; 1.0822x over previous
//
#include <hip/hip_runtime.h>
#include <hip/hip_bf16.h>
#include <stdint.h>

#define L_DIM 384
#define MD    256      // M_DIM
#define CC    32       // C
#define ZD    128      // Z_DIM
#define NB    512      // N (batch) = K of the big GEMM
#define K2    1024     // C*C
#define MROWS 12288    // L*C

typedef __attribute__((ext_vector_type(4))) float  f32x4;
typedef __attribute__((ext_vector_type(8))) short  bf16x8;

typedef __attribute__((address_space(1))) unsigned char* gcp;
typedef __attribute__((address_space(3))) unsigned char* lcp;

#define SBAR()  __builtin_amdgcn_s_barrier()
#define LGKM0() asm volatile("s_waitcnt lgkmcnt(0)" ::: "memory")
#define VMW(n)  asm volatile("s_waitcnt vmcnt(" #n ")" ::: "memory")
#define PRIO1() __builtin_amdgcn_s_setprio(1)
#define PRIO0() __builtin_amdgcn_s_setprio(0)

__device__ __forceinline__ unsigned short f2bf(float x) {
    union { float f; unsigned u; } v; v.f = x;
    unsigned r = v.u + 0x7fffu + ((v.u >> 16) & 1u);   // round-to-nearest-even
    return (unsigned short)(r >> 16);
}

__device__ __forceinline__ uint2 pack4(unsigned short a, unsigned short b,
                                       unsigned short c, unsigned short d) {
    uint2 r; r.x = (unsigned)a | ((unsigned)b << 16);
    r.y = (unsigned)c | ((unsigned)d << 16); return r;
}

// ---------------------------------------------------------------------------
// prep: pack w3 into MFMA B-fragment order w3frag[ks][zg][lane][8] where the
// fragment k-index k2p encodes k2' = b*32 + a (b-major!), so the op tile can be
// written b-major (vectorized 8B stores). Original w3 row = a*C + b.
// Also pack w1/w2 into wfrag[ks][nf][lane][8] for ln_proj.
__global__ __launch_bounds__(256) void prep_kernel(
    const float* __restrict__ w1, const float* __restrict__ w2,
    const float* __restrict__ w3,
    unsigned short* __restrict__ w3frag, unsigned short* __restrict__ wfrag)
{
    int idx = blockIdx.x * 256 + threadIdx.x;          // 147456 total
    if (idx < 131072) {
        int e = idx & 7, lane = (idx >> 3) & 63, zg = (idx >> 9) & 7, ks = idx >> 12;
        int k2p = ks * 32 + ((lane >> 4) << 3) + e;    // k2' = b*32 + a
        int wrow = (k2p & 31) * 32 + (k2p >> 5);       // = a*32 + b
        int z  = zg * 16 + (lane & 15);
        w3frag[idx] = f2bf(w3[(size_t)wrow * ZD + z]);
    } else {
        int j = idx - 131072;                           // 16384
        int e = j & 7, lane = (j >> 3) & 63, nf = (j >> 9) & 3, ks = j >> 11;
        int c = nf * 16 + (lane & 15);
        int d = ks * 32 + ((lane >> 4) << 3) + e;
        float v = (c < CC) ? w2[d * CC + c] : w1[d * CC + (c - CC)];
        wfrag[j] = f2bf(v);
    }
}

// ---------------------------------------------------------------------------
// Kernel A: LayerNorm + dual projection (a = o@w2+b2, b = o@w1+b1) via MFMA.
__global__ __launch_bounds__(256, 4) void ln_proj_kernel(
    const float* __restrict__ mm, const float* __restrict__ gamma, const float* __restrict__ beta,
    const unsigned short* __restrict__ wfrag,
    const float* __restrict__ b1, const float* __restrict__ b2,
    unsigned short* __restrict__ At, unsigned short* __restrict__ Bt)
{
    __shared__ alignas(16) char o_b[32768];            // [64 rows][512 B] swizzled

    const int tid = threadIdx.x, wv = tid >> 6, lane = tid & 63;
    const int l0 = blockIdx.y * 2;
    const int n0 = blockIdx.x * 32;

    const int l_loc = wv >> 1;
    const int nbase = (wv & 1) << 4;
    const int l_g = l0 + l_loc;
    f32x4 g4 = *(const f32x4*)(gamma + lane * 4);
    f32x4 e4 = *(const f32x4*)(beta + lane * 4);

    #pragma unroll 4
    for (int r = 0; r < 16; ++r) {
        int row_loc = wv * 16 + r;
        int n_g = n0 + nbase + r;
        const float* src = mm + ((size_t)n_g * L_DIM + l_g) * MD + lane * 4;
        f32x4 x = *(const f32x4*)src;
        float s  = x[0] + x[1] + x[2] + x[3];
        float s2 = x[0]*x[0] + x[1]*x[1] + x[2]*x[2] + x[3]*x[3];
        #pragma unroll
        for (int off = 32; off > 0; off >>= 1) {
            s  += __shfl_xor(s,  off);
            s2 += __shfl_xor(s2, off);
        }
        float mu  = s * (1.0f / MD);
        float var = s2 * (1.0f / MD) - mu * mu;
        float rs  = rsqrtf(var + 1e-5f);
        unsigned short o0 = f2bf((x[0] - mu) * rs * g4[0] + e4[0]);
        unsigned short o1 = f2bf((x[1] - mu) * rs * g4[1] + e4[1]);
        unsigned short o2 = f2bf((x[2] - mu) * rs * g4[2] + e4[2]);
        unsigned short o3 = f2bf((x[3] - mu) * rs * g4[3] + e4[3]);
        *(uint2*)(o_b + row_loc * 512 + ((lane * 8) ^ ((row_loc & 7) << 4))) = pack4(o0, o1, o2, o3);
    }
    // wave-private rows -> no barrier needed

    f32x4 acc[4] = {{0,0,0,0},{0,0,0,0},{0,0,0,0},{0,0,0,0}};
    const int lrow = lane & 15;
    const int kq16 = (lane >> 4) << 4;
    const int arow = wv * 16 + lrow;
    #pragma unroll
    for (int ks = 0; ks < 8; ++ks) {
        bf16x8 a = *(const bf16x8*)(o_b + arow * 512 + ((ks * 64 + kq16) ^ ((arow & 7) << 4)));
        #pragma unroll
        for (int nf = 0; nf < 4; ++nf) {
            bf16x8 b = *(const bf16x8*)(wfrag + (size_t)((ks * 4 + nf) * 64 + lane) * 8);
            acc[nf] = __builtin_amdgcn_mfma_f32_16x16x32_bf16(a, b, acc[nf], 0, 0, 0);
        }
    }

    const int rr0 = wv * 16 + ((lane >> 4) << 2);
    const int n_gw = n0 + (rr0 & 31);
    const int l_gw = l0 + (rr0 >> 5);
    #pragma unroll
    for (int nf = 0; nf < 4; ++nf) {
        int c = nf * 16 + lrow;
        float bias = (c < CC) ? b2[c] : b1[c - CC];
        unsigned short ob0 = f2bf(acc[nf][0] + bias);
        unsigned short ob1 = f2bf(acc[nf][1] + bias);
        unsigned short ob2 = f2bf(acc[nf][2] + bias);
        unsigned short ob3 = f2bf(acc[nf][3] + bias);
        unsigned short* dst = ((c < CC) ? At : Bt) + (size_t)(l_gw * CC + (c & 31)) * NB + n_gw;
        *(uint2*)dst = pack4(ob0, ob1, ob2, ob3);
    }
}

// ---------------------------------------------------------------------------
// Kernel B: 256x256 op-tile GEMM, K=512, 8-phase schedule, counted vmcnt,
// peeled tail (no wasted stages), XCD-swizzled blocks, fused w3 epilogue with
// vectorized b-major op writes + 2-deep register-pipelined z-loop.
__global__ __launch_bounds__(512, 2) void opm_kernel(
    const unsigned short* __restrict__ At, const unsigned short* __restrict__ Bt,
    const unsigned short* __restrict__ w3frag, const float* __restrict__ b3,
    float* __restrict__ Z)
{
    __shared__ alignas(128) char smem[131072];         // A:[2][256][64] B:[2][256][64]
    char* const Ab = smem;
    char* const Bb = smem + 65536;

    const int tid = threadIdx.x, wv = tid >> 6, lane = tid & 63;

    // T1: XCD-aware remap. 48 i-tiles = 8 XCDs x 6-wide i-bands; within an XCD
    // walk j-major so the 1.5 MB A-band stays L2-resident and B(j) is reused 6x.
    const int lin = blockIdx.y * 48 + blockIdx.x;
    const int xcd = lin & 7, chunk = lin >> 3;         // chunk in [0,288)
    const int i0 = (xcd * 6 + (chunk % 6)) * 256;
    const int j0 = (chunk / 6) * 256;

    const int lrow = lane & 15;
    const int kq16 = (lane >> 4) << 4;
    const int wr = (wv >> 2) * 128, wc = (wv & 3) * 64;

    auto stage = [&](const unsigned short* __restrict__ src, int tile0, int kt,
                     int half, int isA) {
        #pragma unroll
        for (int q = 0; q < 2; ++q) {
            int rl0 = q * 64 + wv * 8;
            int rl  = rl0 + (lane >> 3);
            int rc  = isA ? ((rl  & 63) + ((rl  >> 6) << 7) + half * 64)
                          : ((rl  & 31) + ((rl  >> 5) << 6) + half * 32);
            int rc0 = isA ? ((rl0 & 63) + ((rl0 >> 6) << 7) + half * 64)
                          : ((rl0 & 31) + ((rl0 >> 5) << 6) + half * 32);
            const unsigned short* g = src + (size_t)(tile0 + rc) * NB + kt * 64
                                      + (((lane & 7) ^ (lane >> 3)) << 3);
            char* l = (isA ? Ab : Bb) + (kt & 1) * 32768 + rc0 * 128;  // wave-uniform
            __builtin_amdgcn_global_load_lds((gcp)g, (lcp)l, 16, 0, 0);
        }
    };

    f32x4 acc[8][4] = {};
    bf16x8 av[8], bl[4], bh[4];

    auto rdA = [&](const char* ab, int qrow) {
        #pragma unroll
        for (int mfl = 0; mfl < 4; ++mfl) {
            int row = wr + qrow * 64 + mfl * 16 + lrow;
            const char* p = ab + row * 128;
            av[mfl*2+0] = *(const bf16x8*)(p + ((     kq16) ^ ((row & 7) << 4)));
            av[mfl*2+1] = *(const bf16x8*)(p + ((64 + kq16) ^ ((row & 7) << 4)));
        }
    };
    auto rdB = [&](const char* bb, int qcol, bf16x8* bv) {
        #pragma unroll
        for (int nfl = 0; nfl < 2; ++nfl) {
            int col = wc + qcol * 32 + nfl * 16 + lrow;
            const char* p = bb + col * 128;
            bv[nfl*2+0] = *(const bf16x8*)(p + ((     kq16) ^ ((col & 7) << 4)));
            bv[nfl*2+1] = *(const bf16x8*)(p + ((64 + kq16) ^ ((col & 7) << 4)));
        }
    };
    auto MM = [&](bf16x8* bv, int mbase, int nbase) {
        #pragma unroll
        for (int mfl = 0; mfl < 4; ++mfl)
            #pragma unroll
            for (int nfl = 0; nfl < 2; ++nfl)
                #pragma unroll
                for (int ks = 0; ks < 2; ++ks)
                    acc[mbase+mfl][nbase+nfl] = __builtin_amdgcn_mfma_f32_16x16x32_bf16(
                        av[mfl*2+ks], bv[nfl*2+ks], acc[mbase+mfl][nbase+nfl], 0, 0, 0);
    };

    // --- prologue: stage kt0 + kt1, retire kt0, keep kt1 in flight ---
    stage(At, i0, 0, 0, 1); stage(At, i0, 0, 1, 1);
    stage(Bt, j0, 0, 0, 0); stage(Bt, j0, 0, 1, 0);
    stage(At, i0, 1, 0, 1); stage(At, i0, 1, 1, 1);
    stage(Bt, j0, 1, 0, 0); stage(Bt, j0, 1, 1, 0);
    VMW(8);
    SBAR();

    const char* a0 = Ab;           const char* b0 = Bb;
    const char* a1 = Ab + 32768;   const char* b1 = Bb + 32768;

    // --- main loop: t = 0..2, K-tiles (2t, 2t+1), stages (2t+2, 2t+3) ---
    for (int t = 0; t < 3; ++t) {
        const int ktc = 2*t + 2, ktd = 2*t + 3;
        // P0
        rdA(a0, 0); rdB(b0, 0, bl);
        SBAR(); LGKM0(); PRIO1(); MM(bl, 0, 0); PRIO0(); SBAR();
        // P1
        rdB(b0, 1, bh); stage(At, i0, ktc, 0, 1);
        SBAR(); LGKM0(); PRIO1(); MM(bh, 0, 2); PRIO0(); SBAR();
        // P2
        rdA(a0, 1); stage(Bt, j0, ktc, 0, 0);
        SBAR(); LGKM0(); PRIO1(); MM(bh, 4, 2); PRIO0(); SBAR();
        // P3
        stage(Bt, j0, ktc, 1, 0);
        SBAR(); LGKM0(); PRIO1(); MM(bl, 4, 0); PRIO0(); VMW(6); SBAR();
        // P4
        rdA(a1, 0); rdB(b1, 0, bl); stage(At, i0, ktc, 1, 1);
        SBAR(); LGKM0(); PRIO1(); MM(bl, 0, 0); PRIO0(); SBAR();
        // P5
        rdB(b1, 1, bh); stage(At, i0, ktd, 0, 1);
        SBAR(); LGKM0(); PRIO1(); MM(bh, 0, 2); PRIO0(); SBAR();
        // P6
        rdA(a1, 1); stage(Bt, j0, ktd, 0, 0);
        SBAR(); LGKM0(); PRIO1(); MM(bh, 4, 2); PRIO0(); SBAR();
        // P7
        stage(Bt, j0, ktd, 1, 0); stage(At, i0, ktd, 1, 1);
        SBAR(); LGKM0(); PRIO1(); MM(bl, 4, 0); PRIO0(); VMW(8); SBAR();
    }

    // --- peeled tail: K-tiles 6,7 — no staging, drain at TP3 ---
    // TP0
    rdA(a0, 0); rdB(b0, 0, bl);
    SBAR(); LGKM0(); PRIO1(); MM(bl, 0, 0); PRIO0(); SBAR();
    // TP1
    rdB(b0, 1, bh);
    SBAR(); LGKM0(); PRIO1(); MM(bh, 0, 2); PRIO0(); SBAR();
    // TP2
    rdA(a0, 1);
    SBAR(); LGKM0(); PRIO1(); MM(bh, 4, 2); PRIO0(); SBAR();
    // TP3
    SBAR(); LGKM0(); PRIO1(); MM(bl, 4, 0); PRIO0(); VMW(0); SBAR();
    // TP4
    rdA(a1, 0); rdB(b1, 0, bl);
    SBAR(); LGKM0(); PRIO1(); MM(bl, 0, 0); PRIO0(); SBAR();
    // TP5
    rdB(b1, 1, bh);
    SBAR(); LGKM0(); PRIO1(); MM(bh, 0, 2); PRIO0(); SBAR();
    // TP6
    rdA(a1, 1);
    SBAR(); LGKM0(); PRIO1(); MM(bh, 4, 2); PRIO0(); SBAR();
    // TP7
    SBAR(); LGKM0(); PRIO1(); MM(bl, 4, 0); PRIO0(); SBAR();
    // all global_load_lds drained (TP3), all ds_reads retired (TP7 barrier)

    // ---- fused w3 epilogue ----
    char* const opb = smem;                            // 64 pairs x 2048 B
    const int pfb = (wv >> 2) * 2, zgb = (wv & 3) * 2;
    const int row0 = pfb * 16 + lrow, row1 = row0 + 16;
    const int lq = lane >> 4;

    auto ldW = [&](int ks, int zg) -> bf16x8 {
        return *(const bf16x8*)(w3frag + (size_t)((ks * 8 + zg) * 64 + lane) * 8);
    };
    auto ldP = [&](int row, int ks) -> bf16x8 {
        int g = ks * 4 + lq;
        int b = g >> 2, jj = g & 3;
        int inner = (b * 64 + jj * 16) ^ (((b >> 1) & 7) << 4) ^ ((row & 7) << 4);
        return *(const bf16x8*)(opb + row * 2048 + inner);
    };

    // early-issue first w3 loads (hide under op-write)
    bf16x8 wA0 = ldW(0, zgb), wA1 = ldW(0, zgb + 1);
    bf16x8 wB0 = ldW(1, zgb), wB1 = ldW(1, zgb + 1);

    // write op tile (scaled, bf16), b-major k2' = b*32+a -> 8B vector stores
    const float scale = 1.0f / (float)NB;
    #pragma unroll
    for (int mf = 0; mf < 8; ++mf) {
        #pragma unroll
        for (int nf = 0; nf < 4; ++nf) {
            int col = wc + nf * 16 + lrow;
            int b = col & 31;
            int row = wr + mf * 16 + ((lane >> 4) << 2);
            int pl = ((row >> 5) << 3) | (col >> 5);
            int a0e = row & 31;                        // 4-aligned
            int inner = (b * 64 + a0e * 2) ^ (((b >> 1) & 7) << 4) ^ ((pl & 7) << 4);
            *(uint2*)(opb + pl * 2048 + inner) =
                pack4(f2bf(acc[mf][nf][0] * scale), f2bf(acc[mf][nf][1] * scale),
                      f2bf(acc[mf][nf][2] * scale), f2bf(acc[mf][nf][3] * scale));
        }
    }
    __syncthreads();

    // z-loop: 2-deep software pipeline (w3 from L2, op from LDS)
    f32x4 acc2[2][2] = {};
    bf16x8 pA0 = ldP(row0, 0), pA1 = ldP(row1, 0);
    bf16x8 pB0 = ldP(row0, 1), pB1 = ldP(row1, 1);
    for (int ks = 0; ks < 32; ks += 2) {
        bf16x8 wN0 = {}, wN1 = {}, pN0 = {}, pN1 = {};
        bf16x8 wM0 = {}, wM1 = {}, pM0 = {}, pM1 = {};
        if (ks + 2 < 32) {
            wN0 = ldW(ks + 2, zgb); wN1 = ldW(ks + 2, zgb + 1);
            pN0 = ldP(row0, ks + 2); pN1 = ldP(row1, ks + 2);
            wM0 = ldW(ks + 3, zgb); wM1 = ldW(ks + 3, zgb + 1);
            pM0 = ldP(row0, ks + 3); pM1 = ldP(row1, ks + 3);
        }
        PRIO1();
        acc2[0][0] = __builtin_amdgcn_mfma_f32_16x16x32_bf16(pA0, wA0, acc2[0][0], 0, 0, 0);
        acc2[0][1] = __builtin_amdgcn_mfma_f32_16x16x32_bf16(pA0, wA1, acc2[0][1], 0, 0, 0);
        acc2[1][0] = __builtin_amdgcn_mfma_f32_16x16x32_bf16(pA1, wA0, acc2[1][0], 0, 0, 0);
        acc2[1][1] = __builtin_amdgcn_mfma_f32_16x16x32_bf16(pA1, wA1, acc2[1][1], 0, 0, 0);
        acc2[0][0] = __builtin_amdgcn_mfma_f32_16x16x32_bf16(pB0, wB0, acc2[0][0], 0, 0, 0);
        acc2[0][1] = __builtin_amdgcn_mfma_f32_16x16x32_bf16(pB0, wB1, acc2[0][1], 0, 0, 0);
        acc2[1][0] = __builtin_amdgcn_mfma_f32_16x16x32_bf16(pB1, wB0, acc2[1][0], 0, 0, 0);
        acc2[1][1] = __builtin_amdgcn_mfma_f32_16x16x32_bf16(pB1, wB1, acc2[1][1], 0, 0, 0);
        PRIO0();
        wA0 = wN0; wA1 = wN1; pA0 = pN0; pA1 = pN1;
        wB0 = wM0; wB1 = wM1; pB0 = pM0; pB1 = pM1;
    }

    // write z
    const int pq = (lane >> 4) << 2;
    #pragma unroll
    for (int p = 0; p < 2; ++p) {
        #pragma unroll
        for (int zi = 0; zi < 2; ++zi) {
            int zc = (zgb + zi) * 16 + lrow;
            float bias = b3[zc];
            #pragma unroll
            for (int rr = 0; rr < 4; ++rr) {
                int pl = (pfb + p) * 16 + pq + rr;
                int ii = (i0 >> 5) + (pl >> 3);
                int jj = (j0 >> 5) + (pl & 7);
                Z[((size_t)ii * L_DIM + jj) * ZD + zc] = acc2[p][zi][rr] + bias;
            }
        }
    }
}

// ---------------------------------------------------------------------------
extern "C" void kernel_launch(void* const* d_in, const int* in_sizes, int n_in,
                              void* d_out, int out_size, void* d_ws, size_t ws_size,
                              hipStream_t stream)
{
    const float* mm    = (const float*)d_in[0];
    const float* gamma = (const float*)d_in[1];
    const float* beta  = (const float*)d_in[2];
    const float* w1    = (const float*)d_in[3];
    const float* b1    = (const float*)d_in[4];
    const float* w2    = (const float*)d_in[5];
    const float* b2    = (const float*)d_in[6];
    const float* w3    = (const float*)d_in[7];
    const float* b3    = (const float*)d_in[8];

    unsigned short* At     = (unsigned short*)d_ws;                  // 12288x512
    unsigned short* Bt     = At + (size_t)MROWS * NB;                // 12288x512
    unsigned short* w3frag = Bt + (size_t)MROWS * NB;                // 131072
    unsigned short* wfrag  = w3frag + 131072;                        // 16384

    prep_kernel<<<576, 256, 0, stream>>>(w1, w2, w3, w3frag, wfrag);
    ln_proj_kernel<<<dim3(16, 192), 256, 0, stream>>>(mm, gamma, beta, wfrag, b1, b2, At, Bt);
    opm_kernel<<<dim3(48, 48), 512, 0, stream>>>(At, Bt, w3frag, b3, (float*)d_out);
}